// Round 11
// baseline (560.489 us; speedup 1.0000x reference)
//
#include <hip/hip_runtime.h>
#include <hip/hip_bf16.h>

typedef __hip_bfloat16 bf16;
typedef short s16x8 __attribute__((ext_vector_type(8)));
typedef float f32x4 __attribute__((ext_vector_type(4)));

#define NSEQ 2048
#define DIM  1024
#define CTXD 768
#define INNER 1024
#define NH 16
#define DH 64
#define NB 2
#define TOK (NB*NSEQ)
#define MCTX 77
#define CTOK (NB*MCTX)
#define VSTR_X 128   // padded V^T stride for cross-attn

__device__ __forceinline__ void gload_lds16(const void* g, void* lds) {
  __builtin_amdgcn_global_load_lds(
      (const __attribute__((address_space(1))) unsigned int*)g,
      (__attribute__((address_space(3))) unsigned int*)lds, 16, 0, 0);
}

// ---------- merged preprocessing ----------
__device__ __forceinline__ void wtile(float (*tile)[33], const float* __restrict__ W,
                                      bf16* __restrict__ WT, int K, int N, int t, int REMAP) {
  const int nkx = K >> 5;
  const int kx = t % nkx, ny = t / nkx;
  const int r = threadIdx.x >> 5, c = threadIdx.x & 31;
  const int k0 = kx * 32, n0 = ny * 32;
#pragma unroll
  for (int i = 0; i < 4; ++i)
    tile[r + i*8][c] = W[(size_t)(k0 + r + i*8) * N + n0 + c];
  __syncthreads();
#pragma unroll
  for (int i = 0; i < 4; ++i) {
    int n = n0 + r + i*8;
    if (REMAP == 2) {
      const int f = (n < 4096) ? n : n - 4096;
      n = ((f >> 5) << 6) + ((n < 4096) ? 0 : 32) + (f & 31);
    }
    WT[(size_t)n * K + k0 + c] = __float2bfloat16(tile[c][r + i*8]);
  }
}

#define PB1  1024
#define PB2  2048
#define PB3  3072
#define PB4  4096
#define PB5  5120
#define PB6  5888
#define PB7  6656
#define PB8  7680
#define PB9  15872
#define PB10 19968
#define PB11 20430
#define PB12 20462
#define PTOT 20590

__global__ __launch_bounds__(256)
void prep_kernel(const float* __restrict__ Wq1, const float* __restrict__ Wk1,
                 const float* __restrict__ Wv1, const float* __restrict__ Wo1,
                 const float* __restrict__ Wq2, const float* __restrict__ Wk2,
                 const float* __restrict__ Wv2, const float* __restrict__ Wo2,
                 const float* __restrict__ Wp,  const float* __restrict__ Wf,
                 const float* __restrict__ bp,  const float* __restrict__ ctx,
                 bf16* wqkvT, bf16* wo1T, bf16* wq2T, bf16* wkv2T, bf16* wo2T,
                 bf16* wpT, bf16* wfT, float* bpi, bf16* ctxb, float4* vz) {
  __shared__ float tile[32][33];
  const int bid = blockIdx.x;
  if (bid < PB1)        wtile(tile, Wq1, wqkvT,                         1024, 1024, bid,        0);
  else if (bid < PB2)   wtile(tile, Wk1, wqkvT + (size_t)1024 * 1024,   1024, 1024, bid - PB1,  0);
  else if (bid < PB3)   wtile(tile, Wv1, wqkvT + (size_t)2048 * 1024,   1024, 1024, bid - PB2,  0);
  else if (bid < PB4)   wtile(tile, Wo1, wo1T,                          1024, 1024, bid - PB3,  0);
  else if (bid < PB5)   wtile(tile, Wq2, wq2T,                          1024, 1024, bid - PB4,  0);
  else if (bid < PB6)   wtile(tile, Wk2, wkv2T,                          768, 1024, bid - PB5,  0);
  else if (bid < PB7)   wtile(tile, Wv2, wkv2T + (size_t)1024 * 768,     768, 1024, bid - PB6,  0);
  else if (bid < PB8)   wtile(tile, Wo2, wo2T,                          1024, 1024, bid - PB7,  0);
  else if (bid < PB9)   wtile(tile, Wp,  wpT,                           1024, 8192, bid - PB8,  2);
  else if (bid < PB10)  wtile(tile, Wf,  wfT,                           4096, 1024, bid - PB9,  0);
  else if (bid < PB11) {
    const int i = (bid - PB10) * 256 + threadIdx.x;
    ctxb[i] = __float2bfloat16(ctx[i]);
  } else if (bid < PB12) {
    const int i = (bid - PB11) * 256 + threadIdx.x;
    const int f = (i < 4096) ? i : i - 4096;
    const int n = ((f >> 5) << 6) + ((i < 4096) ? 0 : 32) + (f & 31);
    bpi[n] = bp[i];
  } else {
    const int i = (bid - PB12) * 256 + threadIdx.x;
    vz[i] = make_float4(0.f, 0.f, 0.f, 0.f);
  }
}

// ---------- LayerNorm fp32 -> bf16 ----------
__global__ __launch_bounds__(256)
void ln_kernel(const float* __restrict__ x, const float* __restrict__ gw,
               const float* __restrict__ bw, bf16* __restrict__ out) {
  const int row = blockIdx.x;
  const int t = threadIdx.x;
  const float4 xv = ((const float4*)(x + (size_t)row * DIM))[t];
  float s = xv.x + xv.y + xv.z + xv.w;
  float q = xv.x*xv.x + xv.y*xv.y + xv.z*xv.z + xv.w*xv.w;
#pragma unroll
  for (int m = 1; m < 64; m <<= 1) { s += __shfl_xor(s, m); q += __shfl_xor(q, m); }
  __shared__ float red[8];
  const int lane = t & 63, w = t >> 6;
  if (lane == 0) { red[w] = s; red[4 + w] = q; }
  __syncthreads();
  s = red[0] + red[1] + red[2] + red[3];
  q = red[4] + red[5] + red[6] + red[7];
  const float mean = s * (1.f / DIM);
  const float var = q * (1.f / DIM) - mean * mean;
  const float rs = rsqrtf(var + 1e-5f);
  const float4 gv = ((const float4*)gw)[t];
  const float4 bv = ((const float4*)bw)[t];
  union { bf16 h[4]; uint2 u; } o;
  o.h[0] = __float2bfloat16((xv.x - mean) * rs * gv.x + bv.x);
  o.h[1] = __float2bfloat16((xv.y - mean) * rs * gv.y + bv.y);
  o.h[2] = __float2bfloat16((xv.z - mean) * rs * gv.z + bv.z);
  o.h[3] = __float2bfloat16((xv.w - mean) * rs * gv.w + bv.w);
  ((uint2*)(out + (size_t)row * DIM))[t] = o.u;
}

// ---------- GEMM with double-buffered LDS + counted vmcnt (T3-min/T4) ----------
// EPI 0: bf16 o0 = v*scale
// EPI 2: fp32 o0 = v + bias + resid
// EPI 4: GEGLU pair-in-lane (Wp remap 2)
// EPI 5: QKV fused; EPI 6: KV fused
template<int EPI, int BN>
__global__ __launch_bounds__(256)
void gemm_bt(const bf16* __restrict__ A, const bf16* __restrict__ Bt,
             void* __restrict__ o0, void* __restrict__ o1, void* __restrict__ o2,
             const float* __restrict__ bias, const float* __restrict__ resid,
             int M, int Nn, int K, float scale) {
  constexpr int NT = BN / 32;
  constexpr int LPT = 4 + NT;            // loads per thread per K-tile
  __shared__ bf16 Als[2][128 * 64];
  __shared__ bf16 Bls[2][BN * 64];
  const int tid = threadIdx.x;
  const int lane = tid & 63;
  const int w = tid >> 6;
  const int g = lane >> 4, r16 = lane & 15;
  const int tm = blockIdx.x * 128, tn = blockIdx.y * BN;
  const int wm = (w >> 1) * 64, wn = (w & 1) * (BN / 2);

  f32x4 acc[4][NT];
#pragma unroll
  for (int i = 0; i < 4; ++i)
#pragma unroll
    for (int j = 0; j < NT; ++j) acc[i][j] = (f32x4){0.f, 0.f, 0.f, 0.f};

  auto stage = [&](int kt, int buf) {
#pragma unroll
    for (int i = 0; i < 4; ++i) {
      const int slot = (w * 4 + i) * 64 + lane;
      const int row = slot >> 3;
      const int sch = (slot & 7) ^ (row & 7);
      int ar = tm + row; ar = ar < M ? ar : M - 1;
      gload_lds16(A + (size_t)ar * K + kt + sch * 8, (char*)Als[buf] + (w * 4 + i) * 1024);
    }
#pragma unroll
    for (int i = 0; i < NT; ++i) {
      const int slot = (w * NT + i) * 64 + lane;
      const int row = slot >> 3;
      const int sch = (slot & 7) ^ (row & 7);
      gload_lds16(Bt + (size_t)(tn + row) * K + kt + sch * 8, (char*)Bls[buf] + (w * NT + i) * 1024);
    }
  };

  const int ntk = K >> 6;
  stage(0, 0);
  for (int tk = 0; tk < ntk; ++tk) {
    const int cur = tk & 1;
    if (tk + 1 < ntk) {
      stage((tk + 1) << 6, cur ^ 1);                 // next-tile loads fly during compute
      asm volatile("s_waitcnt vmcnt(%0)" :: "i"(LPT) : "memory");  // wait tile tk only
    } else {
      asm volatile("s_waitcnt vmcnt(0)" ::: "memory");
    }
    __builtin_amdgcn_s_barrier();                    // all waves: buf[cur] ready
    __builtin_amdgcn_sched_barrier(0);
    const char* als = (const char*)Als[cur];
    const char* bls = (const char*)Bls[cur];
#pragma unroll
    for (int kk = 0; kk < 2; ++kk) {
      s16x8 af[4], bfr[NT];
#pragma unroll
      for (int mt = 0; mt < 4; ++mt) {
        const int row = wm + mt * 16 + r16;
        const int ch = (kk * 4 + g) ^ (row & 7);
        af[mt] = *(const s16x8*)(als + row * 128 + ch * 16);
      }
#pragma unroll
      for (int nt = 0; nt < NT; ++nt) {
        const int row = wn + nt * 16 + r16;
        const int ch = (kk * 4 + g) ^ (row & 7);
        bfr[nt] = *(const s16x8*)(bls + row * 128 + ch * 16);
      }
#pragma unroll
      for (int mt = 0; mt < 4; ++mt)
#pragma unroll
        for (int nt = 0; nt < NT; ++nt)
          acc[mt][nt] = __builtin_amdgcn_mfma_f32_16x16x32_bf16(af[mt], bfr[nt], acc[mt][nt], 0, 0, 0);
    }
    __builtin_amdgcn_s_barrier();                    // all waves done reading buf[cur]
    __builtin_amdgcn_sched_barrier(0);
  }

  if constexpr (EPI == 4) {
    const int base = tn + wn;
#pragma unroll
    for (int nt = 0; nt < 2; ++nt) {
      const int cu = base + nt * 16 + r16;
      const float bu = bias[cu];
      const float bg = bias[cu + 32];
      const int f = (base >> 1) + nt * 16 + r16;
#pragma unroll
      for (int mt = 0; mt < 4; ++mt) {
        const int row0 = tm + wm + mt * 16 + 4 * g;
#pragma unroll
        for (int j = 0; j < 4; ++j) {
          const float u  = acc[mt][nt][j] + bu;
          const float gg = acc[mt][nt + 2][j] + bg;
          const float ge = 0.5f * gg * (1.f + erff(gg * 0.70710678118654752f));
          ((bf16*)o0)[(size_t)(row0 + j) * (Nn >> 1) + f] = __float2bfloat16(u * ge);
        }
      }
    }
  } else {
#pragma unroll
    for (int mt = 0; mt < 4; ++mt) {
      const int row0 = tm + wm + mt * 16 + 4 * g;
#pragma unroll
      for (int nt = 0; nt < NT; ++nt) {
        const int col = tn + wn + nt * 16 + r16;
#pragma unroll
        for (int j = 0; j < 4; ++j) {
          const int row = row0 + j;
          if (row >= M) continue;
          const float v = acc[mt][nt][j];
          if (EPI == 0) {
            ((bf16*)o0)[(size_t)row * Nn + col] = __float2bfloat16(v * scale);
          } else if (EPI == 2) {
            ((float*)o0)[(size_t)row * Nn + col] = v + bias[col] + resid[(size_t)row * Nn + col];
          } else if (EPI == 5) {
            const int seg = tn >> 10;
            const int lcol = col - (seg << 10);
            if (seg == 0) {
              ((bf16*)o0)[(size_t)row * INNER + lcol] = __float2bfloat16(v * 0.125f);
            } else if (seg == 1) {
              ((bf16*)o1)[(size_t)row * INNER + lcol] = __float2bfloat16(v);
            } else {
              const int b = row >> 11, i = row & (NSEQ - 1);
              ((bf16*)o2)[((size_t)(b * INNER + lcol)) * NSEQ + i] = __float2bfloat16(v);
            }
          } else if (EPI == 6) {
            const int seg = tn >> 10;
            const int lcol = col - (seg << 10);
            if (seg == 0) {
              ((bf16*)o0)[(size_t)row * INNER + lcol] = __float2bfloat16(v);
            } else {
              const int b = row / MCTX, i = row - b * MCTX;
              ((bf16*)o2)[((size_t)(b * INNER + lcol)) * VSTR_X + i] = __float2bfloat16(v);
            }
          }
        }
      }
    }
  }
}

// ---------- flash attention, QBLK=128, no-max softmax + MFMA-folded row sums ----------
// Row-sum rides an extra PV tile whose V fragment is a register CONSTANT
// (col 64 = ones): saves 2 LDS reads/wave-tile on the saturated LDS pipe.
__global__ __launch_bounds__(256)
void attn_kernel(const bf16* __restrict__ q, const bf16* __restrict__ k,
                 const bf16* __restrict__ vT, bf16* __restrict__ out,
                 int m_kv, int vstr) {
  __shared__ bf16 Kls[64 * 64];
  __shared__ bf16 Vls[64 * 64];
  __shared__ bf16 Pls[4][32 * 64];

  const int tid = threadIdx.x, lane = tid & 63, w = tid >> 6;
  const int g = lane >> 4, r16 = lane & 15;
  const int qt = blockIdx.x, h = blockIdx.y, b = blockIdx.z;

  s16x8 qf[2][2];
#pragma unroll
  for (int mt = 0; mt < 2; ++mt) {
    const int qrow = qt * 128 + w * 32 + mt * 16 + r16;
    const bf16* qb_ = q + ((size_t)(b * NSEQ + qrow)) * INNER + h * DH;
    qf[mt][0] = *(const s16x8*)(qb_ + 8 * g);
    qf[mt][1] = *(const s16x8*)(qb_ + 32 + 8 * g);
  }

  // register B-fragment for the sum column: V^T[64+r16][*] = (r16==0) ? 1 : 0
  const short ov = (r16 == 0) ? (short)0x3F80 : (short)0;
  const s16x8 onesf = {ov, ov, ov, ov, ov, ov, ov, ov};

  f32x4 acc[2][5];
#pragma unroll
  for (int mt = 0; mt < 2; ++mt)
#pragma unroll
    for (int nt = 0; nt < 5; ++nt) acc[mt][nt] = (f32x4){0.f, 0.f, 0.f, 0.f};

  const int ntiles = (m_kv + 63) >> 6;
  int4 kreg[2], vreg[2];

  auto prefetch = [&](int kt) {
#pragma unroll
    for (int i = 0; i < 2; ++i) {
      const int slot = i * 256 + tid;
      const int row = slot >> 3;
      const int sch = (slot & 7) ^ (row & 7);
      const int key = kt * 64 + row;
      kreg[i] = (key < m_kv)
          ? *(const int4*)(k + ((size_t)(b * m_kv + key)) * INNER + h * DH + sch * 8)
          : (int4){0, 0, 0, 0};
      vreg[i] = *(const int4*)(vT + ((size_t)(b * INNER + h * DH + row)) * vstr + kt * 64 + sch * 8);
    }
  };

  prefetch(0);
  bf16* pw = &Pls[w][0];

  for (int kt = 0; kt < ntiles; ++kt) {
    const bool full = (kt * 64 + 64) <= m_kv;
    __syncthreads();
#pragma unroll
    for (int i = 0; i < 2; ++i) {
      const int slot = i * 256 + tid;
      *(int4*)((char*)Kls + slot * 16) = kreg[i];
      *(int4*)((char*)Vls + slot * 16) = vreg[i];
    }
    __syncthreads();
    if (kt + 1 < ntiles) prefetch(kt + 1);

    // S = Q K^T
    f32x4 s4[2][4];
#pragma unroll
    for (int mt = 0; mt < 2; ++mt)
#pragma unroll
      for (int nt = 0; nt < 4; ++nt) s4[mt][nt] = (f32x4){0.f, 0.f, 0.f, 0.f};
#pragma unroll
    for (int kk = 0; kk < 2; ++kk) {
      s16x8 kf[4];
#pragma unroll
      for (int nt = 0; nt < 4; ++nt) {
        const int row = nt * 16 + r16;
        const int ch = (kk * 4 + g) ^ (row & 7);
        kf[nt] = *(const s16x8*)((const char*)Kls + row * 128 + ch * 16);
      }
#pragma unroll
      for (int mt = 0; mt < 2; ++mt)
#pragma unroll
        for (int nt = 0; nt < 4; ++nt)
          s4[mt][nt] = __builtin_amdgcn_mfma_f32_16x16x32_bf16(qf[mt][kk], kf[nt], s4[mt][nt], 0, 0, 0);
    }
    if (!full) {
#pragma unroll
      for (int nt = 0; nt < 4; ++nt) {
        const int key = kt * 64 + nt * 16 + r16;
        if (key >= m_kv) {
#pragma unroll
          for (int mt = 0; mt < 2; ++mt) {
            s4[mt][nt][0] = -1e30f; s4[mt][nt][1] = -1e30f;
            s4[mt][nt][2] = -1e30f; s4[mt][nt][3] = -1e30f;
          }
        }
      }
    }

    // P = exp(S); swizzle XOR on FULL column offset (no add-carry into row bits)
#pragma unroll
    for (int mt = 0; mt < 2; ++mt) {
#pragma unroll
      for (int j = 0; j < 4; ++j) {
        const int prow = mt * 16 + 4 * g + j;
        const int rowbase = prow * 128;
        const int sw = (prow & 7) << 4;
#pragma unroll
        for (int nt = 0; nt < 4; ++nt) {
          const float p = __expf(s4[mt][nt][j]);
          const int byte = rowbase + ((nt * 32 + r16 * 2) ^ sw);
          *(bf16*)((char*)pw + byte) = __float2bfloat16(p);
        }
      }
    }

    // O += P @ [V | ones-col]
#pragma unroll
    for (int kk = 0; kk < 2; ++kk) {
      s16x8 vf[4];
#pragma unroll
      for (int nt = 0; nt < 4; ++nt) {
        const int row = nt * 16 + r16;
        const int ch = (kk * 4 + g) ^ (row & 7);
        vf[nt] = *(const s16x8*)((const char*)Vls + row * 128 + ch * 16);
      }
#pragma unroll
      for (int mt = 0; mt < 2; ++mt) {
        const int prow = mt * 16 + r16;
        const int pch = (kk * 4 + g) ^ (prow & 7);
        const s16x8 pa = *(const s16x8*)((const char*)pw + prow * 128 + pch * 16);
#pragma unroll
        for (int nt = 0; nt < 4; ++nt)
          acc[mt][nt] = __builtin_amdgcn_mfma_f32_16x16x32_bf16(pa, vf[nt], acc[mt][nt], 0, 0, 0);
        acc[mt][4] = __builtin_amdgcn_mfma_f32_16x16x32_bf16(pa, onesf, acc[mt][4], 0, 0, 0);
      }
    }
  }

  // normalize: row sums live in col 0 of the extra tile
#pragma unroll
  for (int mt = 0; mt < 2; ++mt) {
#pragma unroll
    for (int j = 0; j < 4; ++j) {
      const float rs = 1.f / __shfl(acc[mt][4][j], lane & 48);
      const int row = qt * 128 + w * 32 + mt * 16 + 4 * g + j;
#pragma unroll
      for (int nt = 0; nt < 4; ++nt) {
        const int col = h * DH + nt * 16 + r16;
        out[((size_t)(b * NSEQ + row)) * INNER + col] = __float2bfloat16(acc[mt][nt][j] * rs);
      }
    }
  }
}

extern "C" void kernel_launch(void* const* d_in, const int* in_sizes, int n_in,
                              void* d_out, int out_size, void* d_ws, size_t ws_size,
                              hipStream_t stream) {
  const float* x    = (const float*)d_in[0];
  const float* ctx  = (const float*)d_in[1];
  const float* ln1g = (const float*)d_in[2];
  const float* ln1b = (const float*)d_in[3];
  const float* Wq1  = (const float*)d_in[4];
  const float* Wk1  = (const float*)d_in[5];
  const float* Wv1  = (const float*)d_in[6];
  const float* Wo1  = (const float*)d_in[7];
  const float* bo1  = (const float*)d_in[8];
  const float* ln2g = (const float*)d_in[9];
  const float* ln2b = (const float*)d_in[10];
  const float* Wq2  = (const float*)d_in[11];
  const float* Wk2  = (const float*)d_in[12];
  const float* Wv2  = (const float*)d_in[13];
  const float* Wo2  = (const float*)d_in[14];
  const float* bo2  = (const float*)d_in[15];
  const float* ln3g = (const float*)d_in[16];
  const float* ln3b = (const float*)d_in[17];
  const float* Wp   = (const float*)d_in[18];
  const float* bp   = (const float*)d_in[19];
  const float* Wf   = (const float*)d_in[20];
  const float* bfo  = (const float*)d_in[21];

  char* ws = (char*)d_ws;
  size_t off = 0;
  auto alloc = [&](size_t bytes) { char* p = ws + off; off += (bytes + 255) & ~(size_t)255; return p; };
  bf16* wqkvT = (bf16*)alloc((size_t)3072 * 1024 * 2);
  bf16* wo1T  = (bf16*)alloc((size_t)1024 * 1024 * 2);
  bf16* wq2T  = (bf16*)alloc((size_t)1024 * 1024 * 2);
  bf16* wkv2T = (bf16*)alloc((size_t)2048 * 768 * 2);
  bf16* wo2T  = (bf16*)alloc((size_t)1024 * 1024 * 2);
  bf16* wpT   = (bf16*)alloc((size_t)8192 * 1024 * 2);
  bf16* wfT   = (bf16*)alloc((size_t)1024 * 4096 * 2);
  float* bpi  = (float*)alloc((size_t)8192 * 4);
  bf16* ctxb  = (bf16*)alloc((size_t)CTOK * CTXD * 2);
  bf16* hb    = (bf16*)alloc((size_t)TOK * DIM * 2);
  bf16* qb    = (bf16*)alloc((size_t)TOK * INNER * 2);
  bf16* kb    = (bf16*)alloc((size_t)TOK * INNER * 2);
  bf16* vTb   = (bf16*)alloc((size_t)NB * INNER * NSEQ * 2);
  bf16* vTb2  = (bf16*)alloc((size_t)NB * INNER * VSTR_X * 2);
  bf16* ao    = (bf16*)alloc((size_t)TOK * INNER * 2);
  float* xbuf = (float*)alloc((size_t)TOK * DIM * 4);
  bf16* ffin  = (bf16*)alloc((size_t)TOK * 4096 * 2);

  const dim3 blk(256);
  prep_kernel<<<dim3(PTOT), blk, 0, stream>>>(Wq1, Wk1, Wv1, Wo1, Wq2, Wk2, Wv2, Wo2,
                                              Wp, Wf, bp, ctx,
                                              wqkvT, wo1T, wq2T, wkv2T, wo2T,
                                              wpT, wfT, bpi, ctxb, (float4*)vTb2);

  // block 1: self-attention
  ln_kernel<<<dim3(TOK), blk, 0, stream>>>(x, ln1g, ln1b, hb);
  gemm_bt<5, 128><<<dim3(32, 24), blk, 0, stream>>>(hb, wqkvT, qb, kb, vTb, nullptr, nullptr, TOK, 3072, 1024, 1.f);
  attn_kernel<<<dim3(16, 16, 2), blk, 0, stream>>>(qb, kb, vTb, ao, NSEQ, NSEQ);
  gemm_bt<2, 64><<<dim3(32, 16), blk, 0, stream>>>(ao, wo1T, xbuf, nullptr, nullptr, bo1, x, TOK, 1024, 1024, 1.f);

  // block 2: cross-attention
  ln_kernel<<<dim3(TOK), blk, 0, stream>>>(xbuf, ln2g, ln2b, hb);
  gemm_bt<0, 64><<<dim3(32, 16), blk, 0, stream>>>(hb, wq2T, qb, nullptr, nullptr, nullptr, nullptr, TOK, 1024, 1024, 0.125f);
  gemm_bt<6, 64><<<dim3(2, 32), blk, 0, stream>>>(ctxb, wkv2T, kb, nullptr, vTb2, nullptr, nullptr, CTOK, 2048, 768, 1.f);
  attn_kernel<<<dim3(16, 16, 2), blk, 0, stream>>>(qb, kb, vTb2, ao, MCTX, VSTR_X);
  gemm_bt<2, 64><<<dim3(32, 16), blk, 0, stream>>>(ao, wo2T, xbuf, nullptr, nullptr, bo2, xbuf, TOK, 1024, 1024, 1.f);

  // block 3: GEGLU FFN
  ln_kernel<<<dim3(TOK), blk, 0, stream>>>(xbuf, ln3g, ln3b, hb);
  gemm_bt<4, 128><<<dim3(32, 64), blk, 0, stream>>>(hb, wpT, ffin, nullptr, nullptr, bpi, nullptr, TOK, 8192, 1024, 1.f);
  gemm_bt<2, 64><<<dim3(32, 16), blk, 0, stream>>>(ffin, wfT, (float*)d_out, nullptr, nullptr, bfo, xbuf, TOK, 1024, 4096, 1.f);

  (void)in_sizes; (void)n_in; (void)out_size; (void)ws_size;
}